// Round 8
// baseline (507.701 us; speedup 1.0000x reference)
//
#include <hip/hip_runtime.h>
#include <hip/hip_bf16.h>
#include <stdint.h>

// out = relu(x @ W_up^T) @ W_down^T + x @ W_expert
// (softmax-of-top-k weights sum to 1 -> MoE gating is a mathematical no-op)
//
// 256x256-tile bf16 MFMA GEMM, BK=64, 512 threads (8 waves 2Mx4N), 16x16x32
// MFMA (proven 0-conflict fragment pattern). A staged via global_load_lds into
// XOR-swizzled LDS (64 KiB double-buffered); B fragments loaded DIRECTLY from
// global (L2-resident strip) into registers, one tile ahead -> LDS read
// traffic -33%, LDS writes -50%. One counted vmcnt(8) + one barrier per tile.
//
// vm ledger per tile (issue order enforced by "memory" fence):
//   [Ast(t+1) x4] ... [Bfrag(t+1) x8]  -> pending 12
//   end-of-tile vmcnt(8) retires Ast(t+1) (aged ~full tile);
//   Bfrag(t+1) stays in flight; compiler auto-waits vmcnt(4) before the first
//   MFMA use of bva next tile (it tracks register loads precisely).

#define DIM 2048
#define MTOT 16384

typedef unsigned short u16;
typedef __bf16 bf16x8 __attribute__((ext_vector_type(8)));
typedef float f32x4 __attribute__((ext_vector_type(4)));

__device__ __forceinline__ u16 f2bf(float f) {
    union { float f; unsigned int u; } a; a.f = f;
    unsigned int u = a.u;
    unsigned int r = (u + 0x7fffu + ((u >> 16) & 1u)) >> 16;  // RNE
    return (u16)r;
}

__device__ __forceinline__ bf16x8 frag_load(const void* p) {
    union { uint4 u; bf16x8 b; } x;
    x.u = *(const uint4*)p;
    return x.b;
}

// ---------------------------------------------------------------------------
// Merged fp32->bf16 conversions (x, W_up, W_down) in one grid-strided kernel.
__global__ void cvt_all(const float* __restrict__ x, const float* __restrict__ Wu,
                        const float* __restrict__ Wd, u16* __restrict__ Abig,
                        u16* __restrict__ Wup, u16* __restrict__ Bbig) {
    const long NX = (long)MTOT * DIM / 4;   // 8388608 float4 items
    const long NW = (long)DIM * DIM / 4;    // 1048576
    long i = (long)blockIdx.x * blockDim.x + threadIdx.x;
    long stride = (long)gridDim.x * blockDim.x;
    for (; i < NX + 2 * NW; i += stride) {
        const float* src; u16* dst; int dld, doff; long e;
        if (i < NX)            { src = x;  dst = Abig; dld = 4096; doff = 2048; e = i << 2; }
        else if (i < NX + NW)  { src = Wu; dst = Wup;  dld = 2048; doff = 0;    e = (i - NX) << 2; }
        else                   { src = Wd; dst = Bbig; dld = 4096; doff = 0;    e = (i - NX - NW) << 2; }
        long row = e >> 11;
        int col = (int)(e & 2047);
        float4 v = *(const float4*)(src + e);
        union { u16 q[4]; uint2 d; } u;
        u.q[0] = f2bf(v.x); u.q[1] = f2bf(v.y);
        u.q[2] = f2bf(v.z); u.q[3] = f2bf(v.w);
        *(uint2*)(dst + row * (long)dld + doff + col) = u.d;
    }
}

// W_expert is [K,N] applied as x @ W_expert; need B^T layout [N,K] into B_big
// columns 2048..4095.
__global__ void cvt_transpose(const float* __restrict__ W, u16* __restrict__ dst) {
    __shared__ float t[32][33];
    int bx = blockIdx.x & 63;
    int by = blockIdx.x >> 6;
    int x = threadIdx.x & 31, y = threadIdx.x >> 5;
    #pragma unroll
    for (int j = 0; j < 32; j += 8)
        t[y + j][x] = W[(size_t)(by * 32 + y + j) * 2048 + bx * 32 + x];
    __syncthreads();
    #pragma unroll
    for (int j = 0; j < 32; j += 8)
        dst[(size_t)(bx * 32 + y + j) * 4096 + 2048 + by * 32 + x] = f2bf(t[x][y + j]);
}

// ---------------------------------------------------------------------------
// 256^2 GEMM: C[M,N] = A[M,K] @ B[N,K]^T, 16x16x32 MFMA.
// LDS: A only, 2 buffers x 2 halves x 128 rows x 128 B = 64 KiB.
// Swizzle: (r,c) at byte r*128 + ((2c) ^ ((r&7)<<4)).
// B fragments: per-lane global dwordx4 loads (lanes l,l+16,l+32,l+48 share a
// 64B line), issued one tile ahead right after last use.
template <int MODE>
__global__ __launch_bounds__(512, 2)
void gemm256(const u16* __restrict__ A, const u16* __restrict__ B,
             void* __restrict__ Cptr, int lda, int ldb, int K) {
    __shared__ char lds[2][32768];

    const int tid  = threadIdx.x;
    const int lane = tid & 63;
    const int wv   = tid >> 6;   // 0..7
    const int wr   = wv >> 2;    // 0..1  (row 64-block within each 128-half)
    const int wc   = wv & 3;     // 0..3  (col 32-strip within each 128-half)

    // XCD-aware bijective swizzle (grid=512, divisible by 8)
    int bid = blockIdx.x;
    int cpx = gridDim.x >> 3;
    int swz = (bid & 7) * cpx + (bid >> 3);
    int tile_n = swz & 7;        // N/256 = 8
    int tile_m = swz >> 3;       // M/256 = 64

    const int rowA0 = tile_m * 256;
    const int rowB0 = tile_n * 256;

    // A staging: per half 2 loads/thread. Load j: linear LDS byte j*8192+tid*16
    // -> row r = j*64 + (tid>>3), linear col (tid&7)*16. Pre-swizzled source:
    const int r_sub = tid >> 3;
    const int c_src = ((tid & 7) ^ (r_sub & 7)) << 3;  // element offset
    const u16* pAb = A + (size_t)(rowA0 + r_sub) * lda + c_src;

    // B fragment base: row rowB0 + (wc<<5) + (lane&15), elem col (lane>>4)*8.
    const u16* pBf = B + (size_t)(rowB0 + (wc << 5) + (lane & 15)) * ldb
                       + ((lane >> 4) << 3);

    f32x4 acc[2][2][4][2];
    #pragma unroll
    for (int a = 0; a < 2; ++a)
        #pragma unroll
        for (int b = 0; b < 2; ++b)
            #pragma unroll
            for (int m = 0; m < 4; ++m)
                #pragma unroll
                for (int n = 0; n < 2; ++n)
                    acc[a][b][m][n] = (f32x4){0.f, 0.f, 0.f, 0.f};

    bf16x8 av[4][2];    // current A half's fragments (4 m x 2 kk)
    bf16x8 bva[2][2];   // B half 0 fragments (rows rowB0+wc*32+n*16+lane&15)
    bf16x8 bvb[2][2];   // B half 1 fragments (+128 rows)
    const int kA = (lane >> 4) << 4;   // byte base of k-part, kk=0

#define STAGE_A(H, KOFF, BUF) do {                                              \
    const u16* _s = pAb + (size_t)((H) * 128) * lda + (KOFF);                   \
    __builtin_amdgcn_global_load_lds(                                           \
        (const __attribute__((address_space(1))) void*)_s,                      \
        (__attribute__((address_space(3))) void*)((char*)lds[BUF] + (H)*16384 + (wv<<10)), \
        16, 0, 0);                                                              \
    __builtin_amdgcn_global_load_lds(                                           \
        (const __attribute__((address_space(1))) void*)(_s + (size_t)64 * lda), \
        (__attribute__((address_space(3))) void*)((char*)lds[BUF] + (H)*16384 + 8192 + (wv<<10)), \
        16, 0, 0);                                                              \
  } while (0)

#define DSREAD_A(MH, CUR) do {                                                  \
    _Pragma("unroll")                                                           \
    for (int m = 0; m < 4; ++m) {                                               \
        int ra = (wr << 6) + (m << 4) + (lane & 15);                            \
        const char* _b = (const char*)lds[CUR] + (MH)*16384 + (ra << 7);        \
        int sw = (ra & 7) << 4;                                                 \
        av[m][0] = frag_load(_b + (kA ^ sw));                                   \
        av[m][1] = frag_load(_b + ((64 + kA) ^ sw));                            \
    } } while (0)

// B fragments for a K-tile whose first element column is KOFFE (elems).
#define LOAD_BVA(KOFFE) do {                                                    \
    const u16* _p = pBf + (KOFFE);                                              \
    bva[0][0] = frag_load(_p);                                                  \
    bva[0][1] = frag_load(_p + 32);                                             \
    bva[1][0] = frag_load(_p + (size_t)16 * ldb);                               \
    bva[1][1] = frag_load(_p + (size_t)16 * ldb + 32);                          \
  } while (0)

#define LOAD_BVB(KOFFE) do {                                                    \
    const u16* _p = pBf + (size_t)128 * ldb + (KOFFE);                          \
    bvb[0][0] = frag_load(_p);                                                  \
    bvb[0][1] = frag_load(_p + 32);                                             \
    bvb[1][0] = frag_load(_p + (size_t)16 * ldb);                               \
    bvb[1][1] = frag_load(_p + (size_t)16 * ldb + 32);                          \
  } while (0)

#define MFMA_Q(MH, NH, BV) do {                                                 \
    __builtin_amdgcn_s_setprio(1);                                              \
    _Pragma("unroll")                                                           \
    for (int m = 0; m < 4; ++m)                                                 \
        _Pragma("unroll")                                                       \
        for (int n = 0; n < 2; ++n) {                                           \
            acc[MH][NH][m][n] = __builtin_amdgcn_mfma_f32_16x16x32_bf16(        \
                av[m][0], BV[n][0], acc[MH][NH][m][n], 0, 0, 0);                \
            acc[MH][NH][m][n] = __builtin_amdgcn_mfma_f32_16x16x32_bf16(        \
                av[m][1], BV[n][1], acc[MH][NH][m][n], 0, 0, 0);                \
        }                                                                       \
    __builtin_amdgcn_s_setprio(0);                                              \
  } while (0)

#define WAIT_VM(N) asm volatile("s_waitcnt vmcnt(" #N ")" ::: "memory")
#define FENCE() asm volatile("" ::: "memory")
#define BAR() __builtin_amdgcn_s_barrier()

    // Prologue: stage A(0); fence; load B(0) frags -> pending [Ast x4, Bfrag x8].
    STAGE_A(0, 0, 0);
    STAGE_A(1, 0, 0);
    FENCE();
    LOAD_BVA(0);
    LOAD_BVB(0);
    WAIT_VM(8);   // retire A-stages of tile 0; B frags keep flying
    BAR();

    const int nK = K >> 6;
    int cur = 0;
    for (int t = 0; t < nK - 1; ++t) {
        const int koff = (t + 1) << 6;
        const int nxt = cur ^ 1;
        DSREAD_A(0, cur);
        STAGE_A(0, koff, nxt);
        STAGE_A(1, koff, nxt);
        FENCE();                      // pin: A-stages before B-frag loads
        // (compiler auto-inserts vmcnt(4) here before first bva use)
        MFMA_Q(0, 0, bva);
        MFMA_Q(0, 1, bvb);
        DSREAD_A(1, cur);
        MFMA_Q(1, 1, bvb);            // last bvb use
        LOAD_BVB(koff);               // t+1's B half-1 frags
        MFMA_Q(1, 0, bva);            // last bva use
        LOAD_BVA(koff);               // t+1's B half-0 frags
        WAIT_VM(8);                   // retire Ast(t+1) (aged ~full tile)
        BAR();
        cur = nxt;
    }

    // Last tile: no prefetch. Pending: Bfrag(last) x8 (compiler waits on use).
    DSREAD_A(0, cur);
    MFMA_Q(0, 0, bva);
    MFMA_Q(0, 1, bvb);
    DSREAD_A(1, cur);
    MFMA_Q(1, 1, bvb);
    MFMA_Q(1, 0, bva);

    // Epilogue. 16x16 C/D layout: col = lane&15, row = (lane>>4)*4 + reg.
    #pragma unroll
    for (int mh = 0; mh < 2; ++mh)
        #pragma unroll
        for (int m = 0; m < 4; ++m)
            #pragma unroll
            for (int r = 0; r < 4; ++r) {
                int row = rowA0 + mh * 128 + (wr << 6) + (m << 4) + ((lane >> 4) << 2) + r;
                #pragma unroll
                for (int nh = 0; nh < 2; ++nh)
                    #pragma unroll
                    for (int n = 0; n < 2; ++n) {
                        int col = tile_n * 256 + nh * 128 + (wc << 5) + (n << 4) + (lane & 15);
                        float v = acc[mh][nh][m][n][r];
                        if (MODE == 0) {
                            ((u16*)Cptr)[(size_t)row * 4096 + col] = f2bf(fmaxf(v, 0.f));
                        } else {
                            ((float*)Cptr)[(size_t)row * 2048 + col] = v;
                        }
                    }
            }
#undef STAGE_A
#undef DSREAD_A
#undef LOAD_BVA
#undef LOAD_BVB
#undef MFMA_Q
#undef WAIT_VM
#undef FENCE
#undef BAR
}

// ---------------------------------------------------------------------------
extern "C" void kernel_launch(void* const* d_in, const int* in_sizes, int n_in,
                              void* d_out, int out_size, void* d_ws, size_t ws_size,
                              hipStream_t stream) {
    const float* x        = (const float*)d_in[0];
    const float* W_up     = (const float*)d_in[1];
    const float* W_down   = (const float*)d_in[2];
    // d_in[3] = W_gate: unused (softmax over top-k sums to 1 -> gating no-op)
    const float* W_expert = (const float*)d_in[4];

    // Workspace (bf16 as u16):
    //   A_big [16384][4096]: cols 0..2047 = h (GEMM1 output), 2048..4095 = x
    //   B_big [2048][4096] : cols 0..2047 = W_down, 2048..4095 = W_expert^T
    //   W_up_bf [2048][2048]
    u16* Abig = (u16*)d_ws;
    u16* Bbig = Abig + (size_t)MTOT * 4096;
    u16* Wup  = Bbig + (size_t)DIM * 4096;

    cvt_all<<<2048, 256, 0, stream>>>(x, W_up, W_down, Abig, Wup, Bbig);
    cvt_transpose<<<4096, 256, 0, stream>>>(W_expert, Bbig);

    // GEMM1: h = relu(x @ W_up^T) -> bf16 into A_big left half
    gemm256<0><<<512, 512, 0, stream>>>(Abig + 2048, Wup, Abig, 4096, 2048, 2048);
    // GEMM2: out = A_big @ B_big^T = h @ W_down^T + x @ W_expert (fp32)
    gemm256<1><<<512, 512, 0, stream>>>(Abig, Bbig, d_out, 4096, 4096, 4096);
}